// Round 4
// baseline (4728.213 us; speedup 1.0000x reference)
//
#include <hip/hip_runtime.h>
#include <math.h>

#define B_   512
#define T_   2048
#define H_   64
#define NS_  32
#define HH_  128   // 2H
#define G4_  256   // 4H
#define EPSF 1e-5f

typedef _Float16 h2 __attribute__((ext_vector_type(2)));
typedef _Float16 h4 __attribute__((ext_vector_type(4)));
typedef _Float16 h8 __attribute__((ext_vector_type(8)));
union H8u { h8 v; h2 p[4]; };

#if __has_builtin(__builtin_amdgcn_fdot2)
__device__ __forceinline__ float fdot2(h2 a, h2 b, float c) {
    return __builtin_amdgcn_fdot2(a, b, c, false);   // v_dot2_f32_f16
}
#else
__device__ __forceinline__ float fdot2(h2 a, h2 b, float c) {
    return c + (float)a[0] * (float)b[0] + (float)a[1] * (float)b[1];
}
#endif

#if __has_builtin(__builtin_amdgcn_permlane32_swap)
#define HAVE_PLSWAP 1
typedef unsigned int uv2 __attribute__((ext_vector_type(2)));
// one swap serves both columns: returns lane-local sum over both k-halves;
// result lane L holds total for column (n0 + (L>>5)) of this lane-pair.
__device__ __forceinline__ float combine_swap(float a, float b) {
    uv2 r = __builtin_amdgcn_permlane32_swap(
        __float_as_uint(a), __float_as_uint(b), false, false);
    return __uint_as_float(r.x) + __uint_as_float(r.y);
}
#else
#define HAVE_PLSWAP 0
#endif

__device__ __forceinline__ float gelu_f(float x) {
    return 0.5f * x * (1.0f + erff(x * 0.70710678118654752440f));
}
__device__ __forceinline__ float sigmoid_f(float x) {
    return 1.0f / (1.0f + __expf(-x));
}
__device__ __forceinline__ float tanh_f(float x) {
    return 1.0f - 2.0f / (__expf(2.0f * x) + 1.0f);
}

// ---------------------------------------------------------------------------
// Input projection -> packed fp16 x-sequence  seqh[B][T][64]
// ---------------------------------------------------------------------------
__global__ void __launch_bounds__(256) inproj_kernel(
    const float* __restrict__ sensors, const float* __restrict__ W1,
    const float* __restrict__ b1, const float* __restrict__ g1,
    const float* __restrict__ bb1, const float* __restrict__ W2,
    const float* __restrict__ b2, _Float16* __restrict__ seqh)
{
    __shared__ __align__(16) float W1l[NS_ * H_];
    __shared__ __align__(16) float W2l[H_ * H_];
    __shared__ float p1[H_], p2[H_], p3[H_], p4[H_];
    const int tid = threadIdx.x;
    {
        const float4* s1 = (const float4*)W1;
        float4* d1 = (float4*)W1l;
        for (int i = tid; i < NS_ * H_ / 4; i += 256) d1[i] = s1[i];
        const float4* s2 = (const float4*)W2;
        float4* d2 = (float4*)W2l;
        for (int i = tid; i < H_ * H_ / 4; i += 256) d2[i] = s2[i];
        if (tid < H_) { p1[tid] = b1[tid]; p2[tid] = g1[tid];
                        p3[tid] = bb1[tid]; p4[tid] = b2[tid]; }
    }
    __syncthreads();

    const long idx = (long)blockIdx.x * 256 + tid;
    const float* srow = sensors + idx * NS_;
    float sv[NS_];
    #pragma unroll
    for (int q = 0; q < NS_ / 4; ++q) {
        float4 v = *(const float4*)&srow[q * 4];
        sv[q*4+0] = v.x; sv[q*4+1] = v.y; sv[q*4+2] = v.z; sv[q*4+3] = v.w;
    }
    float t1[H_];
    #pragma unroll
    for (int jb = 0; jb < H_ / 4; ++jb) {
        float ax = p1[jb*4+0], ay = p1[jb*4+1], az = p1[jb*4+2], aw = p1[jb*4+3];
        #pragma unroll
        for (int k = 0; k < NS_; ++k) {
            float4 w = *(const float4*)&W1l[k * H_ + jb * 4];
            ax += sv[k]*w.x; ay += sv[k]*w.y; az += sv[k]*w.z; aw += sv[k]*w.w;
        }
        t1[jb*4+0] = ax; t1[jb*4+1] = ay; t1[jb*4+2] = az; t1[jb*4+3] = aw;
    }
    float mean = 0.f;
    #pragma unroll
    for (int j = 0; j < H_; ++j) mean += t1[j];
    mean *= (1.0f / H_);
    float var = 0.f;
    #pragma unroll
    for (int j = 0; j < H_; ++j) { float d = t1[j] - mean; var += d * d; }
    var *= (1.0f / H_);
    const float inv = rsqrtf(var + EPSF);
    #pragma unroll
    for (int j = 0; j < H_; ++j) {
        float nv = (t1[j] - mean) * inv * p2[j] + p3[j];
        t1[j] = gelu_f(nv);
    }
    _Float16* orow = seqh + idx * H_;
    for (int ob = 0; ob < H_ / 4; ++ob) {
        float ax = p4[ob*4+0], ay = p4[ob*4+1];
        float az = p4[ob*4+2], aw = p4[ob*4+3];
        #pragma unroll
        for (int j = 0; j < H_; ++j) {
            float4 w = *(const float4*)&W2l[j * H_ + ob * 4];
            ax += t1[j]*w.x; ay += t1[j]*w.y; az += t1[j]*w.z; aw += t1[j]*w.w;
        }
        h4 o; o[0] = (_Float16)ax; o[1] = (_Float16)ay;
              o[2] = (_Float16)az; o[3] = (_Float16)aw;
        *(h4*)&orow[ob * 4] = o;
    }
}

// ---------------------------------------------------------------------------
// Fused 4-layer pipelined LSTM, 1024 threads = 16 waves = (layer, col-quarter).
// Lane-level k-split: lanes 0-31 take k in [0,64), lanes 32-63 k in [64,128).
//   Per lane: 2 gate cols x 64 k fp16 = 64 weight VGPRs (no AGPR shuttle),
//   4 fdot2 chains x 32 = 128 dot2/step. k-halves combined with
//   v_permlane32_swap (1 swap + 1 add covers both columns of one row).
// Nonlin duty: waves with cq<2 handle (layer l, row cq), lane = hidden unit.
// Pipeline: at step s, layer l processes t = s-l; h hands off via LDS.
// ---------------------------------------------------------------------------
__global__ void __launch_bounds__(1024, 4) lstm_fused_kernel(
    const float* __restrict__ Wg, const float* __restrict__ bg,
    const _Float16* __restrict__ xin,   // [B][T][64] fp16
    _Float16* __restrict__ h3f16,       // in-place h3 output (if h3f32 null)
    float* __restrict__ h3f32)          // fp32 h3 output (preferred)
{
    __shared__ __align__(16) _Float16 combh[4][2][HH_];  // [l][row][x|h] 2 KB
    __shared__ __align__(16) float gbuf[4][2][G4_];      // 8 KB

    const int tid  = threadIdx.x;
    const int wv_  = tid >> 6;              // 0..15
    const int lane = tid & 63;
    const int l    = wv_ >> 2;              // layer
    const int cq   = wv_ & 3;               // column quarter
    const int lp   = lane & 31;             // lane-pair id
    const int kh   = lane >> 5;             // k half (0/1)
    const int kb   = kh * 64;               // k base
    const int n0   = cq * 64 + 2 * lp;      // first owned column

    // ---- fp16-pack weight columns {n0, n0+1}, k in [kb, kb+64) ----
    const float* W = Wg + (size_t)l * HH_ * G4_;
    h2 w0[32], w1[32];
    #pragma unroll
    for (int kk = 0; kk < 32; ++kk) {
        float2 wa = *(const float2*)&W[(kb + 2 * kk)     * G4_ + n0];
        float2 wb = *(const float2*)&W[(kb + 2 * kk + 1) * G4_ + n0];
        h2 a, b;
        a[0] = (_Float16)wa.x; a[1] = (_Float16)wb.x;
        b[0] = (_Float16)wa.y; b[1] = (_Float16)wb.y;
        w0[kk] = a; w1[kk] = b;
    }

    const bool nl  = (cq < 2);              // nonlinearity duty
    const int  row = cq & 1;
    float bi = 0.f, bf = 0.f, bgg = 0.f, bo = 0.f;
    if (nl) {
        bi  = bg[l * G4_ + lane];
        bf  = bg[l * G4_ + 64  + lane];
        bgg = bg[l * G4_ + 128 + lane];
        bo  = bg[l * G4_ + 192 + lane];
    }
    const long rowbase = ((long)(blockIdx.x * 2 + row)) * T_ * H_;

    float c_reg = 0.f;
    if (nl) {
        combh[l][row][64 + lane] = (_Float16)0.f;           // h_l(-1) = 0
        if (l == 0) combh[0][row][lane] = xin[rowbase + lane]; // x_0(0)
    }
    __syncthreads();

    const h8* cp0 = (const h8*)&combh[l][0][kb];
    const h8* cp1 = (const h8*)&combh[l][1][kb];

    for (int s = 0; s < T_ + 3; ++s) {
        const bool act = (s >= l) && (s - l < T_);
        _Float16 xnext = (_Float16)0.f;
        if (act) {
            if (nl && l == 0 && s + 1 < T_)     // prefetch under the matmul
                xnext = xin[rowbase + (long)(s + 1) * H_ + lane];
            float a00 = 0.f, a01 = 0.f, a10 = 0.f, a11 = 0.f;
            #pragma unroll
            for (int i = 0; i < 8; ++i) {
                H8u u0, u1;
                u0.v = cp0[i];                  // 2-addr/wave reads: free alias
                u1.v = cp1[i];
                #pragma unroll
                for (int j = 0; j < 4; ++j) {
                    const int kk = i * 4 + j;
                    a00 = fdot2(u0.p[j], w0[kk], a00);
                    a01 = fdot2(u0.p[j], w1[kk], a01);
                    a10 = fdot2(u1.p[j], w0[kk], a10);
                    a11 = fdot2(u1.p[j], w1[kk], a11);
                }
            }
#if HAVE_PLSWAP
            gbuf[l][0][n0 + kh] = combine_swap(a00, a01);
            gbuf[l][1][n0 + kh] = combine_swap(a10, a11);
#else
            float g00 = a00 + __shfl_xor(a00, 32, 64);
            float g01 = a01 + __shfl_xor(a01, 32, 64);
            float g10 = a10 + __shfl_xor(a10, 32, 64);
            float g11 = a11 + __shfl_xor(a11, 32, 64);
            if (kh == 0) {
                float2 r0; r0.x = g00; r0.y = g01;
                float2 r1; r1.x = g10; r1.y = g11;
                *(float2*)&gbuf[l][0][n0] = r0;
                *(float2*)&gbuf[l][1][n0] = r1;
            }
#endif
        }
        __syncthreads();
        if (act && nl) {
            const int t = s - l;
            const float ig = sigmoid_f(gbuf[l][row][lane]        + bi);
            const float fg = sigmoid_f(gbuf[l][row][64  + lane]  + bf);
            const float g_ = tanh_f(   gbuf[l][row][128 + lane]  + bgg);
            const float og = sigmoid_f(gbuf[l][row][192 + lane]  + bo);
            c_reg = fg * c_reg + ig * g_;
            const float hn = og * tanh_f(c_reg);
            const _Float16 hh = (_Float16)hn;
            combh[l][row][64 + lane] = hh;                      // h_l(t)
            if (l < 3) combh[l + 1][row][lane] = hh;            // x_{l+1}(t)
            else if (h3f32) h3f32[rowbase + (long)t * H_ + lane] = hn;
            else            h3f16[rowbase + (long)t * H_ + lane] = hh;
            if (l == 0 && s + 1 < T_) combh[0][row][lane] = xnext; // x_0(t+1)
        }
        __syncthreads();
    }
}

// ---------------------------------------------------------------------------
// Output projection: y = GELU(LN(h3) @ W_out1 + b_out1) @ W_out2 + b_out2
// ---------------------------------------------------------------------------
__global__ void __launch_bounds__(256) outproj_kernel(
    const _Float16* __restrict__ h16, const float* __restrict__ h32, int use32,
    const float* __restrict__ g2, const float* __restrict__ b2,
    const float* __restrict__ W1, const float* __restrict__ b1,
    const float* __restrict__ W2, const float* __restrict__ b2o,
    float* __restrict__ y)
{
    __shared__ __align__(16) float W1l[H_ * H_];
    __shared__ __align__(16) float W2l[H_ * 4];
    __shared__ float pg[H_], pb[H_], pb1[H_];
    const int tid = threadIdx.x;
    {
        const float4* s1 = (const float4*)W1;
        float4* d1 = (float4*)W1l;
        for (int i = tid; i < H_ * H_ / 4; i += 256) d1[i] = s1[i];
        if (tid < H_) {
            pg[tid] = g2[tid]; pb[tid] = b2[tid]; pb1[tid] = b1[tid];
            float4 w; w.x = W2[tid*3+0]; w.y = W2[tid*3+1]; w.z = W2[tid*3+2]; w.w = 0.f;
            *(float4*)&W2l[tid * 4] = w;
        }
    }
    __syncthreads();

    const long idx = (long)blockIdx.x * 256 + tid;
    float hv[H_];
    if (use32) {
        const float* hrow = h32 + idx * H_;
        #pragma unroll
        for (int q = 0; q < H_ / 4; ++q) {
            float4 v = *(const float4*)&hrow[q * 4];
            hv[q*4+0] = v.x; hv[q*4+1] = v.y; hv[q*4+2] = v.z; hv[q*4+3] = v.w;
        }
    } else {
        const _Float16* hrow = h16 + idx * H_;
        #pragma unroll
        for (int q = 0; q < H_ / 8; ++q) {
            h8 v = *(const h8*)&hrow[q * 8];
            #pragma unroll
            for (int j = 0; j < 8; ++j) hv[q*8+j] = (float)v[j];
        }
    }
    float mean = 0.f;
    #pragma unroll
    for (int j = 0; j < H_; ++j) mean += hv[j];
    mean *= (1.0f / H_);
    float var = 0.f;
    #pragma unroll
    for (int j = 0; j < H_; ++j) { float dd = hv[j] - mean; var += dd * dd; }
    var *= (1.0f / H_);
    const float inv = rsqrtf(var + EPSF);
    #pragma unroll
    for (int j = 0; j < H_; ++j) hv[j] = (hv[j] - mean) * inv * pg[j] + pb[j];

    float y0 = b2o[0], y1 = b2o[1], y2 = b2o[2];
    for (int ob = 0; ob < H_ / 4; ++ob) {
        float ax = pb1[ob*4+0], ay = pb1[ob*4+1];
        float az = pb1[ob*4+2], aw = pb1[ob*4+3];
        #pragma unroll
        for (int j = 0; j < H_; ++j) {
            float4 w = *(const float4*)&W1l[j * H_ + ob * 4];
            ax += hv[j]*w.x; ay += hv[j]*w.y; az += hv[j]*w.z; aw += hv[j]*w.w;
        }
        ax = gelu_f(ax); ay = gelu_f(ay); az = gelu_f(az); aw = gelu_f(aw);
        float4 wa = *(const float4*)&W2l[(ob*4+0) * 4];
        float4 wb = *(const float4*)&W2l[(ob*4+1) * 4];
        float4 wc = *(const float4*)&W2l[(ob*4+2) * 4];
        float4 wd = *(const float4*)&W2l[(ob*4+3) * 4];
        y0 += ax*wa.x + ay*wb.x + az*wc.x + aw*wd.x;
        y1 += ax*wa.y + ay*wb.y + az*wc.y + aw*wd.y;
        y2 += ax*wa.z + ay*wb.z + az*wc.z + aw*wd.z;
    }
    y[idx * 3 + 0] = y0;
    y[idx * 3 + 1] = y1;
    y[idx * 3 + 2] = y2;
}

// ---------------------------------------------------------------------------
extern "C" void kernel_launch(void* const* d_in, const int* in_sizes, int n_in,
                              void* d_out, int out_size, void* d_ws, size_t ws_size,
                              hipStream_t stream)
{
    const float* sensors = (const float*)d_in[0];
    const float* W_in1   = (const float*)d_in[1];
    const float* b_in1   = (const float*)d_in[2];
    const float* ln1_g   = (const float*)d_in[3];
    const float* ln1_b   = (const float*)d_in[4];
    const float* W_in2   = (const float*)d_in[5];
    const float* b_in2   = (const float*)d_in[6];
    const float* Wg      = (const float*)d_in[7];
    const float* bg      = (const float*)d_in[8];
    const float* ln2_g   = (const float*)d_in[9];
    const float* ln2_b   = (const float*)d_in[10];
    const float* W_out1  = (const float*)d_in[11];
    const float* b_out1  = (const float*)d_in[12];
    const float* W_out2  = (const float*)d_in[13];
    const float* b_out2  = (const float*)d_in[14];
    float* y = (float*)d_out;

    const size_t elems = (size_t)B_ * T_ * H_;
    _Float16* seqh = (_Float16*)d_ws;               // 128 MB fp16 x/h buffer
    float* h3f32 = nullptr;
    int use32 = 0;
    if (ws_size >= elems * 2 + elems * 4) {
        h3f32 = (float*)((char*)d_ws + elems * 2);
        use32 = 1;
    }

    inproj_kernel<<<B_ * T_ / 256, 256, 0, stream>>>(
        sensors, W_in1, b_in1, ln1_g, ln1_b, W_in2, b_in2, seqh);
    lstm_fused_kernel<<<B_ / 2, 1024, 0, stream>>>(Wg, bg, seqh, seqh, h3f32);
    outproj_kernel<<<B_ * T_ / 256, 256, 0, stream>>>(
        seqh, h3f32, use32, ln2_g, ln2_b, W_out1, b_out1, W_out2, b_out2, y);
}

// Round 5
// 3171.380 us; speedup vs baseline: 1.4909x; 1.4909x over previous
//
#include <hip/hip_runtime.h>
#include <math.h>

#define B_   512
#define T_   2048
#define H_   64
#define NS_  32
#define HH_  128   // 2H
#define G4_  256   // 4H
#define EPSF 1e-5f

typedef _Float16 half8 __attribute__((ext_vector_type(8)));
typedef _Float16 h4   __attribute__((ext_vector_type(4)));
typedef float    f32x4 __attribute__((ext_vector_type(4)));

__device__ __forceinline__ float gelu_f(float x) {
    return 0.5f * x * (1.0f + erff(x * 0.70710678118654752440f));
}
__device__ __forceinline__ float sigmoid_f(float x) {
    return 1.0f / (1.0f + __expf(-x));
}
__device__ __forceinline__ float tanh_f(float x) {
    return 1.0f - 2.0f / (__expf(2.0f * x) + 1.0f);
}

// ---------------------------------------------------------------------------
// Input projection -> packed fp16 x-sequence  seqh[B][T][64]
// ---------------------------------------------------------------------------
__global__ void __launch_bounds__(256) inproj_kernel(
    const float* __restrict__ sensors, const float* __restrict__ W1,
    const float* __restrict__ b1, const float* __restrict__ g1,
    const float* __restrict__ bb1, const float* __restrict__ W2,
    const float* __restrict__ b2, _Float16* __restrict__ seqh)
{
    __shared__ __align__(16) float W1l[NS_ * H_];
    __shared__ __align__(16) float W2l[H_ * H_];
    __shared__ float p1[H_], p2[H_], p3[H_], p4[H_];
    const int tid = threadIdx.x;
    {
        const float4* s1 = (const float4*)W1;
        float4* d1 = (float4*)W1l;
        for (int i = tid; i < NS_ * H_ / 4; i += 256) d1[i] = s1[i];
        const float4* s2 = (const float4*)W2;
        float4* d2 = (float4*)W2l;
        for (int i = tid; i < H_ * H_ / 4; i += 256) d2[i] = s2[i];
        if (tid < H_) { p1[tid] = b1[tid]; p2[tid] = g1[tid];
                        p3[tid] = bb1[tid]; p4[tid] = b2[tid]; }
    }
    __syncthreads();

    const long idx = (long)blockIdx.x * 256 + tid;
    const float* srow = sensors + idx * NS_;
    float sv[NS_];
    #pragma unroll
    for (int q = 0; q < NS_ / 4; ++q) {
        float4 v = *(const float4*)&srow[q * 4];
        sv[q*4+0] = v.x; sv[q*4+1] = v.y; sv[q*4+2] = v.z; sv[q*4+3] = v.w;
    }
    float t1[H_];
    #pragma unroll
    for (int jb = 0; jb < H_ / 4; ++jb) {
        float ax = p1[jb*4+0], ay = p1[jb*4+1], az = p1[jb*4+2], aw = p1[jb*4+3];
        #pragma unroll
        for (int k = 0; k < NS_; ++k) {
            float4 w = *(const float4*)&W1l[k * H_ + jb * 4];
            ax += sv[k]*w.x; ay += sv[k]*w.y; az += sv[k]*w.z; aw += sv[k]*w.w;
        }
        t1[jb*4+0] = ax; t1[jb*4+1] = ay; t1[jb*4+2] = az; t1[jb*4+3] = aw;
    }
    float mean = 0.f;
    #pragma unroll
    for (int j = 0; j < H_; ++j) mean += t1[j];
    mean *= (1.0f / H_);
    float var = 0.f;
    #pragma unroll
    for (int j = 0; j < H_; ++j) { float d = t1[j] - mean; var += d * d; }
    var *= (1.0f / H_);
    const float inv = rsqrtf(var + EPSF);
    #pragma unroll
    for (int j = 0; j < H_; ++j) {
        float nv = (t1[j] - mean) * inv * p2[j] + p3[j];
        t1[j] = gelu_f(nv);
    }
    _Float16* orow = seqh + idx * H_;
    for (int ob = 0; ob < H_ / 4; ++ob) {
        float ax = p4[ob*4+0], ay = p4[ob*4+1];
        float az = p4[ob*4+2], aw = p4[ob*4+3];
        #pragma unroll
        for (int j = 0; j < H_; ++j) {
            float4 w = *(const float4*)&W2l[j * H_ + ob * 4];
            ax += t1[j]*w.x; ay += t1[j]*w.y; az += t1[j]*w.z; aw += t1[j]*w.w;
        }
        h4 o; o[0] = (_Float16)ax; o[1] = (_Float16)ay;
              o[2] = (_Float16)az; o[3] = (_Float16)aw;
        *(h4*)&orow[ob * 4] = o;
    }
}

// ---------------------------------------------------------------------------
// Fused 4-layer pipelined LSTM via MFMA (16x16x32 f16, fp32 accum).
//   256 blocks x 512 thr (8 waves = layer x col-half); block owns 2 rows.
//   Weights: B-fragments, 128 VGPRs/lane, loaded once (MFMA reads AGPRs
//   natively -> no shuttle). comb=[x|h] per layer: [16 rows][128 k] fp16 in
//   LDS, XOR-swizzled (byte ^= (row&7)<<4) for conflict-free ds_read_b128
//   A-fragments. Rows 2..15 stay zero (M-padding, free).
//   Assumed fragment maps (std gfx9 family):
//     A: lane -> row=lane&15, k = 8*(lane>>4)+j
//     B: lane -> col=lane&15, k = 8*(lane>>4)+j
//     D: lane,reg -> col=lane&15, row=4*(lane>>4)+reg  [m89-verified]
//   Nonlin duty: thread -> unit (l'=tid>>7, row=(tid>>6)&1, u=tid&63).
// ---------------------------------------------------------------------------
__global__ void __launch_bounds__(512, 2) lstm_fused_kernel(
    const float* __restrict__ Wg, const float* __restrict__ bg,
    const _Float16* __restrict__ xin,   // [B][T][64] fp16
    _Float16* __restrict__ h3f16,       // in-place h3 (if h3f32 null)
    float* __restrict__ h3f32)          // fp32 h3 (preferred)
{
    __shared__ __align__(16) char combB[4 * 16 * 256];  // 16 KB, swizzled
    __shared__ __align__(8)  float gbuf[4][G4_][2];     // 8 KB

    const int tid  = threadIdx.x;
    const int wv   = tid >> 6;
    const int lane = tid & 63;
    const int l    = wv >> 1;               // matmul: layer
    const int half = wv & 1;                // matmul: column half
    const int nlayer = tid >> 7;            // nonlin: layer
    const int nrow   = (tid >> 6) & 1;      // nonlin: row
    const int u      = tid & 63;            // nonlin: hidden unit

    // ---- load weight B-fragments (once) ----
    const float* W = Wg + (size_t)l * HH_ * G4_;
    half8 wf[4][8];                          // [k-tile][n-tile]
    #pragma unroll
    for (int kt = 0; kt < 4; ++kt) {
        #pragma unroll
        for (int nt = 0; nt < 8; ++nt) {
            half8 f;
            #pragma unroll
            for (int j = 0; j < 8; ++j) {
                const int k   = kt * 32 + (lane >> 4) * 8 + j;
                const int col = half * 128 + nt * 16 + (lane & 15);
                f[j] = (_Float16)W[k * G4_ + col];
            }
            wf[kt][nt] = f;
        }
    }

    const float* bgp = bg + nlayer * G4_;
    const float bi = bgp[u], bff = bgp[64 + u], bgg = bgp[128 + u], bo = bgp[192 + u];
    const long nrowbase = ((long)(blockIdx.x * 2 + nrow)) * T_ * H_;

    // zero comb (rows 2..15 must stay zero; h(-1)=0)
    for (int i = tid; i < 4 * 16 * 256 / 4; i += 512) ((float*)combB)[i] = 0.f;
    __syncthreads();
    if (nlayer == 0) {                       // stage x_0(0), swizzled
        const _Float16 x0 = xin[nrowbase + u];
        const int byte = nrow * 256 + ((2 * u) ^ ((nrow & 7) << 4));
        *(_Float16*)(combB + byte) = x0;
    }
    __syncthreads();

    float c_reg = 0.f;
    const int arow  = lane & 15;
    const int kgrp  = (lane >> 4) * 16;     // byte offset of lane's 8-fp16 k-group
    const int abase = l * 4096 + arow * 256;
    const int axor  = (arow & 7) << 4;

    for (int s = 0; s < T_ + 3; ++s) {
        const bool mact = (s >= l) && (s - l < T_);
        const bool nact = (s >= nlayer) && (s - nlayer < T_);
        _Float16 xnext = (_Float16)0.f;
        if (nlayer == 0 && s + 1 < T_)       // prefetch x(t+1) under the MFMAs
            xnext = xin[nrowbase + (long)(s + 1) * H_ + u];

        if (mact) {
            half8 af[4];
            #pragma unroll
            for (int kt = 0; kt < 4; ++kt) {
                const int byte = abase + ((kt * 64 + kgrp) ^ axor);
                af[kt] = *(const half8*)(combB + byte);
            }
            f32x4 acc[8];
            #pragma unroll
            for (int nt = 0; nt < 8; ++nt) acc[nt] = (f32x4){0.f, 0.f, 0.f, 0.f};
            #pragma unroll
            for (int kt = 0; kt < 4; ++kt) {
                #pragma unroll
                for (int nt = 0; nt < 8; ++nt)
                    acc[nt] = __builtin_amdgcn_mfma_f32_16x16x32_f16(
                        af[kt], wf[kt][nt], acc[nt], 0, 0, 0);
            }
            if (lane < 16) {                 // D rows 0,1 = regs 0,1 of lanes 0-15
                #pragma unroll
                for (int nt = 0; nt < 8; ++nt) {
                    const int col = half * 128 + nt * 16 + lane;
                    float2 r; r.x = acc[nt][0]; r.y = acc[nt][1];
                    *(float2*)&gbuf[l][col][0] = r;
                }
            }
        }
        __syncthreads();
        if (nact) {
            const int t = s - nlayer;
            const float gi = gbuf[nlayer][u][nrow]       + bi;
            const float gf = gbuf[nlayer][64 + u][nrow]  + bff;
            const float gg = gbuf[nlayer][128 + u][nrow] + bgg;
            const float go = gbuf[nlayer][192 + u][nrow] + bo;
            c_reg = sigmoid_f(gf) * c_reg + sigmoid_f(gi) * tanh_f(gg);
            const float hn = sigmoid_f(go) * tanh_f(c_reg);
            const _Float16 hh = (_Float16)hn;
            const int hb = nlayer * 4096 + nrow * 256 + ((128 + 2 * u) ^ ((nrow & 7) << 4));
            *(_Float16*)(combB + hb) = hh;                       // h_l(t)
            if (nlayer < 3) {                                    // x_{l+1}(t)
                const int xb = (nlayer + 1) * 4096 + nrow * 256 + ((2 * u) ^ ((nrow & 7) << 4));
                *(_Float16*)(combB + xb) = hh;
            } else if (h3f32) h3f32[nrowbase + (long)t * H_ + u] = hn;
              else            h3f16[nrowbase + (long)t * H_ + u] = hh;
            if (nlayer == 0 && s + 1 < T_) {                     // x_0(t+1)
                const int xb = nrow * 256 + ((2 * u) ^ ((nrow & 7) << 4));
                *(_Float16*)(combB + xb) = xnext;
            }
        }
        __syncthreads();
    }
}

// ---------------------------------------------------------------------------
// Output projection: y = GELU(LN(h3) @ W_out1 + b_out1) @ W_out2 + b_out2
// ---------------------------------------------------------------------------
__global__ void __launch_bounds__(256) outproj_kernel(
    const _Float16* __restrict__ h16, const float* __restrict__ h32, int use32,
    const float* __restrict__ g2, const float* __restrict__ b2,
    const float* __restrict__ W1, const float* __restrict__ b1,
    const float* __restrict__ W2, const float* __restrict__ b2o,
    float* __restrict__ y)
{
    __shared__ __align__(16) float W1l[H_ * H_];
    __shared__ __align__(16) float W2l[H_ * 4];
    __shared__ float pg[H_], pb[H_], pb1[H_];
    const int tid = threadIdx.x;
    {
        const float4* s1 = (const float4*)W1;
        float4* d1 = (float4*)W1l;
        for (int i = tid; i < H_ * H_ / 4; i += 256) d1[i] = s1[i];
        if (tid < H_) {
            pg[tid] = g2[tid]; pb[tid] = b2[tid]; pb1[tid] = b1[tid];
            float4 w; w.x = W2[tid*3+0]; w.y = W2[tid*3+1]; w.z = W2[tid*3+2]; w.w = 0.f;
            *(float4*)&W2l[tid * 4] = w;
        }
    }
    __syncthreads();

    const long idx = (long)blockIdx.x * 256 + tid;
    float hv[H_];
    if (use32) {
        const float* hrow = h32 + idx * H_;
        #pragma unroll
        for (int q = 0; q < H_ / 4; ++q) {
            float4 v = *(const float4*)&hrow[q * 4];
            hv[q*4+0] = v.x; hv[q*4+1] = v.y; hv[q*4+2] = v.z; hv[q*4+3] = v.w;
        }
    } else {
        const _Float16* hrow = h16 + idx * H_;
        #pragma unroll
        for (int q = 0; q < H_ / 8; ++q) {
            half8 v = *(const half8*)&hrow[q * 8];
            #pragma unroll
            for (int j = 0; j < 8; ++j) hv[q*8+j] = (float)v[j];
        }
    }
    float mean = 0.f;
    #pragma unroll
    for (int j = 0; j < H_; ++j) mean += hv[j];
    mean *= (1.0f / H_);
    float var = 0.f;
    #pragma unroll
    for (int j = 0; j < H_; ++j) { float dd = hv[j] - mean; var += dd * dd; }
    var *= (1.0f / H_);
    const float inv = rsqrtf(var + EPSF);
    #pragma unroll
    for (int j = 0; j < H_; ++j) hv[j] = (hv[j] - mean) * inv * pg[j] + pb[j];

    float y0 = b2o[0], y1 = b2o[1], y2 = b2o[2];
    for (int ob = 0; ob < H_ / 4; ++ob) {
        float ax = pb1[ob*4+0], ay = pb1[ob*4+1];
        float az = pb1[ob*4+2], aw = pb1[ob*4+3];
        #pragma unroll
        for (int j = 0; j < H_; ++j) {
            float4 w = *(const float4*)&W1l[j * H_ + ob * 4];
            ax += hv[j]*w.x; ay += hv[j]*w.y; az += hv[j]*w.z; aw += hv[j]*w.w;
        }
        ax = gelu_f(ax); ay = gelu_f(ay); az = gelu_f(az); aw = gelu_f(aw);
        float4 wa = *(const float4*)&W2l[(ob*4+0) * 4];
        float4 wb = *(const float4*)&W2l[(ob*4+1) * 4];
        float4 wc = *(const float4*)&W2l[(ob*4+2) * 4];
        float4 wd = *(const float4*)&W2l[(ob*4+3) * 4];
        y0 += ax*wa.x + ay*wb.x + az*wc.x + aw*wd.x;
        y1 += ax*wa.y + ay*wb.y + az*wc.y + aw*wd.y;
        y2 += ax*wa.z + ay*wb.z + az*wc.z + aw*wd.z;
    }
    y[idx * 3 + 0] = y0;
    y[idx * 3 + 1] = y1;
    y[idx * 3 + 2] = y2;
}

// ---------------------------------------------------------------------------
extern "C" void kernel_launch(void* const* d_in, const int* in_sizes, int n_in,
                              void* d_out, int out_size, void* d_ws, size_t ws_size,
                              hipStream_t stream)
{
    const float* sensors = (const float*)d_in[0];
    const float* W_in1   = (const float*)d_in[1];
    const float* b_in1   = (const float*)d_in[2];
    const float* ln1_g   = (const float*)d_in[3];
    const float* ln1_b   = (const float*)d_in[4];
    const float* W_in2   = (const float*)d_in[5];
    const float* b_in2   = (const float*)d_in[6];
    const float* Wg      = (const float*)d_in[7];
    const float* bg      = (const float*)d_in[8];
    const float* ln2_g   = (const float*)d_in[9];
    const float* ln2_b   = (const float*)d_in[10];
    const float* W_out1  = (const float*)d_in[11];
    const float* b_out1  = (const float*)d_in[12];
    const float* W_out2  = (const float*)d_in[13];
    const float* b_out2  = (const float*)d_in[14];
    float* y = (float*)d_out;

    const size_t elems = (size_t)B_ * T_ * H_;
    _Float16* seqh = (_Float16*)d_ws;               // 128 MB fp16 x buffer
    float* h3f32 = nullptr;
    int use32 = 0;
    if (ws_size >= elems * 2 + elems * 4) {
        h3f32 = (float*)((char*)d_ws + elems * 2);
        use32 = 1;
    }

    inproj_kernel<<<B_ * T_ / 256, 256, 0, stream>>>(
        sensors, W_in1, b_in1, ln1_g, ln1_b, W_in2, b_in2, seqh);
    lstm_fused_kernel<<<B_ / 2, 512, 0, stream>>>(Wg, bg, seqh, seqh, h3f32);
    outproj_kernel<<<B_ * T_ / 256, 256, 0, stream>>>(
        seqh, h3f32, use32, ln2_g, ln2_b, W_out1, b_out1, W_out2, b_out2, y);
}